// Round 4
// baseline (278.448 us; speedup 1.0000x reference)
//
#include <hip/hip_runtime.h>
#include <stdint.h>

// Keep IoU arithmetic bit-identical to an IEEE no-FMA reference:
#pragma clang fp contract(off)

#define BB   8
#define NN   2048
#define CC   32
#define WORDS 64           // uint32 words per 2048-bit row mask
#define NBLK 64            // rank blocks of 32
#define NMS_THR 0.45f
#define PRE_THR 0.005f
#define PADI(i) ((((i) >> 5) * 33) + ((i) & 31))   // padded SoA index
#define KPAD(i) ((i) + ((i) >> 4))                 // u64 key pad (kills 8-way b64 conflicts)

// ---------------- K1: per-image adjacency bitmask ----------------
// grid (128, 8): block (x,b) -> rows [x*16, x*16+16); wave -> 4 rows. 4 blocks/CU.
// Lane l owns output word l. Fast rcp path with exact-div fallback in a narrow
// guard band (rcp err ~1e-7 << 2e-5 band) -> decisions bit-identical to IEEE div.
__global__ __launch_bounds__(256) void adj_kernel(const float* __restrict__ bbs,
                                                  uint32_t* __restrict__ adj) {
    __shared__ float sx1[2112], sy1[2112], sx2[2112], sy2[2112];
    const int b = blockIdx.y;
    const int t = threadIdx.x;
    const float4* bp = (const float4*)bbs + (size_t)b * NN;
    for (int i = t; i < NN; i += 256) {
        float4 v = bp[i];
        int p = PADI(i);
        sx1[p] = v.x; sy1[p] = v.y; sx2[p] = v.z; sy2[p] = v.w;
    }
    __syncthreads();

    const int wave = t >> 6, lane = t & 63;
    const int row0 = blockIdx.x * 16 + wave * 4;
    const float THI = 0.45f * 1.00002f;
    const float TLO = 0.45f * 0.99998f;

    float ax1[4], ay1[4], ax2[4], ay2[4], areaA[4];
#pragma unroll
    for (int r = 0; r < 4; ++r) {
        int p = PADI(row0 + r);
        ax1[r] = sx1[p]; ay1[r] = sy1[p]; ax2[r] = sx2[p]; ay2[r] = sy2[p];
        areaA[r] = (ax2[r] - ax1[r]) * (ay2[r] - ay1[r]);
    }
    uint32_t w[4] = {0, 0, 0, 0};
#pragma unroll 4
    for (int j = 0; j < 32; ++j) {
        int p = lane * 33 + j;                 // bank (lane+j)%32: 2-way = free
        float bx1 = sx1[p], by1 = sy1[p], bx2 = sx2[p], by2 = sy2[p];
        float areaB = (bx2 - bx1) * (by2 - by1);
#pragma unroll
        for (int r = 0; r < 4; ++r) {
            float ltx = fmaxf(ax1[r], bx1), lty = fmaxf(ay1[r], by1);
            float rbx = fminf(ax2[r], bx2), rby = fminf(ay2[r], by2);
            float ww = fmaxf(rbx - ltx, 0.0f);
            float hh = fmaxf(rby - lty, 0.0f);
            float inter = ww * hh;
            float uni  = (areaA[r] + areaB) - inter;
            float unim = fmaxf(uni, 1e-12f);
            float q1 = inter * __builtin_amdgcn_rcpf(unim);
            bool hi = q1 > THI;
            bool lo = q1 < TLO;
            bool adjb;
            if (__builtin_expect(__any((int)!(hi || lo)), 0))
                adjb = (inter / unim) > NMS_THR;   // exact IEEE div, rare
            else
                adjb = hi;
            if (adjb) w[r] |= (1u << j);
        }
    }
#pragma unroll
    for (int r = 0; r < 4; ++r) {
        int row = row0 + r;
        uint32_t dmask = (lane == (row >> 5)) ? ~(1u << (row & 31)) : 0xFFFFFFFFu;
        adj[((size_t)b * NN + row) * WORDS + lane] = w[r] & dmask;
    }
}

// ---------------- K2: per-(b,c) single-wave bitonic sort ----------------
// grid 256 x 64 threads. One wave owns the whole sort: no inter-wave barriers.
// Writes ordv (idx | nonzero<<16) to workspace.
__global__ __launch_bounds__(64) void sort_kernel(const float* __restrict__ conf,
                                                  uint32_t* __restrict__ wsOrd) {
    __shared__ unsigned long long keys[2176];   // KPAD(2047)=2174
    const int bc = blockIdx.x;
    const int lane = threadIdx.x;
    const float* cf = conf + (size_t)bc * NN;   // [B,C,N] with C=32 -> bc*N

    for (int i = lane; i < NN; i += 64) {
        float v  = cf[i];
        float vt = (v > PRE_THR) ? v : 0.0f;
        keys[KPAD(i)] = ((unsigned long long)__float_as_uint(vt) << 32) | (uint32_t)(NN - 1 - i);
    }
    __syncthreads();

    for (unsigned k = 2; k <= NN; k <<= 1) {
        for (unsigned j = k >> 1; j > 0; j >>= 1) {
            for (int it = 0; it < 16; ++it) {
                unsigned p  = (unsigned)(it * 64 + lane);
                unsigned i  = ((p & ~(j - 1)) << 1) | (p & (j - 1));
                unsigned ij = i | j;
                unsigned long long a = keys[KPAD(i)], d = keys[KPAD(ij)];
                bool up = ((i & k) == 0);
                unsigned long long mn = (a < d) ? a : d;
                unsigned long long mx = (a < d) ? d : a;
                keys[KPAD(i)]  = up ? mx : mn;     // descending in up-regions
                keys[KPAD(ij)] = up ? mn : mx;
            }
            __syncthreads();   // single wave: compiles to cheap lgkmcnt+barrier
        }
    }

    uint32_t* ov = wsOrd + (size_t)bc * NN;
    for (int r = lane; r < NN; r += 64) {
        unsigned long long kk = keys[KPAD(r)];
        uint32_t idx = (uint32_t)(NN - 1) - (uint32_t)(kk & 0xffffffffu);
        uint32_t nz  = ((uint32_t)(kk >> 32) != 0u) ? 0x10000u : 0u;
        ov[r] = idx | nz;
    }
}

// ---------------- K3: rank-space sub-adjacency extraction ----------------
// grid 2048 x 256: block (bc, chunk-of-8 rank-blocks); 8 blocks/CU -> latency hidden.
// Stores M'[d] = M[d] & (0xFFFFFFFE << d)  (later-rank mask pre-applied).
__global__ __launch_bounds__(256) void extract_kernel(const uint32_t* __restrict__ adj,
                                                      const uint32_t* __restrict__ wsOrd,
                                                      uint32_t* __restrict__ wsM) {
    const int blkid = blockIdx.x;
    const int bc = blkid >> 3, chunk = blkid & 7;
    const int b  = bc >> 5;
    const int t = threadIdx.x, wv = t >> 6, lane = t & 63, e = lane & 31, h = lane >> 5;
    const uint32_t* ov = wsOrd + (size_t)bc * NN;
    const uint32_t* ab = adj + (size_t)b * NN * WORDS;

    for (int blk = chunk * 8 + wv; blk < chunk * 8 + 8; blk += 4) {
        uint32_t ue = ov[blk * 32 + e];
        int widx = (int)((ue & 0xffffu) >> 5);
        int bpos = (int)(ue & 31u);
        uint32_t wb[16];
#pragma unroll
        for (int k = 0; k < 16; ++k) {
            uint32_t ud = ov[blk * 32 + k * 2 + h] & 0xffffu;
            wb[k] = ab[(size_t)ud * WORDS + widx];
        }
        uint32_t vM = 0;
#pragma unroll
        for (int k = 0; k < 16; ++k) {
            unsigned long long bal = __ballot(((wb[k] >> bpos) & 1u) != 0u);
            vM = (lane == 2 * k    ) ? (uint32_t)bal         : vM;
            vM = (lane == 2 * k + 1) ? (uint32_t)(bal >> 32) : vM;
        }
        if (lane < 32)
            wsM[(size_t)bc * NN + blk * 32 + lane] = vM & (0xFFFFFFFEu << lane);
    }
}

// ---------------- K4: serial blocked greedy scan + output ----------------
// grid 256 x 64 threads (one wave). S word l lives in lane l.
__global__ __launch_bounds__(64) void scan_kernel(const float* __restrict__ conf,
                                                  const uint32_t* __restrict__ adj,
                                                  const uint32_t* __restrict__ wsOrd,
                                                  const uint32_t* __restrict__ wsM,
                                                  float* __restrict__ out) {
    const int bc = blockIdx.x;
    const int b  = bc >> 5;
    const int lane = threadIdx.x;
    const uint32_t* ov = wsOrd + (size_t)bc * NN;
    const uint32_t* mv = wsM   + (size_t)bc * NN;
    const uint32_t* const rowp = adj + (size_t)b * NN * WORDS + lane;
    const float* cf = conf + (size_t)bc * NN;
    float* op = out + (size_t)bc * NN;

    uint32_t S = 0;
    uint32_t rbA[32], rbB[32];
    uint32_t u_c = ov[lane & 31];
    uint32_t m_c = mv[lane & 31];
    uint32_t u_n, m_n;
#pragma unroll
    for (int d = 0; d < 32; ++d) {
        int ud = __builtin_amdgcn_readlane((int)u_c, d) & 0xffff;
        rbA[d] = rowp[(size_t)ud * WORDS];
    }

    auto do_block = [&](int blk, uint32_t (&rbC)[32], uint32_t (&rbN)[32]) {
        u_n = 0; m_n = 0;
        if (blk < 63) {
            u_n = ov[(blk + 1) * 32 + (lane & 31)];
            m_n = mv[(blk + 1) * 32 + (lane & 31)];
#pragma unroll
            for (int d = 0; d < 32; ++d) {
                int ud = __builtin_amdgcn_readlane((int)u_n, d) & 0xffff;
                rbN[d] = rowp[(size_t)ud * WORDS];
            }
        }
        int wq  = (int)(((u_c & 0xffffu) >> 5) << 2);
        int bpv = (int)(u_c & 31u);
        int pm  = __builtin_amdgcn_ds_bpermute(wq, (int)S);
        bool a0 = (((u_c >> 16) & 1u) != 0u) && (((pm >> bpv) & 1) == 0);
        uint32_t alive = (uint32_t)__ballot((int)a0);
        if (alive) {
#pragma unroll
            for (int d = 0; d < 32; ++d) {
                uint32_t mk = (uint32_t)__builtin_amdgcn_readlane((int)m_c, d);  // pre-masked
                alive = (alive & (1u << d)) ? (alive & ~mk) : alive;
            }
            uint32_t acc = 0;
#pragma unroll
            for (int d = 0; d < 32; ++d)
                acc |= (alive & (1u << d)) ? rbC[d] : 0u;
            S |= acc;
        }
        u_c = u_n; m_c = m_n;
    };

    for (int blk = 0; blk < NBLK; blk += 2) {
        do_block(blk,     rbA, rbB);
        do_block(blk + 1, rbB, rbA);
    }

    // Output: suppressed-bit lookup via bpermute of register-resident S.
#pragma unroll 4
    for (int it = 0; it < 32; ++it) {
        int i = it * 64 + lane;
        int sw = __builtin_amdgcn_ds_bpermute(((i >> 5) & 63) << 2, (int)S);
        bool sup = (sw >> (i & 31)) & 1;
        float v = cf[i];
        op[i] = (v > PRE_THR && !sup) ? v : 0.0f;
    }
}

// ---------------- Fallback (ws too small): R3 monolithic ----------------
__global__ __launch_bounds__(256) void nms_fallback(const float* __restrict__ conf,
                                                    const uint32_t* __restrict__ adj,
                                                    float* __restrict__ out) {
    __shared__ unsigned long long keys[NN];
    __shared__ uint32_t ordv[NN];
    __shared__ uint32_t Mlds[NBLK * 32];
    __shared__ uint32_t Sarr[WORDS];
    const int bc = blockIdx.x;
    const int b  = bc >> 5;
    const int t  = threadIdx.x;
    const float* cf = conf + (size_t)bc * NN;
    const uint32_t* const abase = adj + (size_t)b * NN * WORDS;

    for (int i = t; i < NN; i += 256) {
        float v  = cf[i];
        float vt = (v > PRE_THR) ? v : 0.0f;
        keys[i] = ((unsigned long long)__float_as_uint(vt) << 32) | (uint32_t)(NN - 1 - i);
    }
    __syncthreads();
    for (unsigned k = 2; k <= NN; k <<= 1)
        for (unsigned j = k >> 1; j > 0; j >>= 1) {
            for (unsigned p = t; p < NN / 2; p += 256) {
                unsigned i  = ((p & ~(j - 1)) << 1) | (p & (j - 1));
                unsigned ij = i | j;
                unsigned long long a = keys[i], d = keys[ij];
                bool up = ((i & k) == 0);
                if (up ? (a < d) : (a > d)) { keys[i] = d; keys[ij] = a; }
            }
            __syncthreads();
        }
    for (int r = t; r < NN; r += 256) {
        unsigned long long kk = keys[r];
        uint32_t idx = (uint32_t)(NN - 1) - (uint32_t)(kk & 0xffffffffu);
        uint32_t nz  = ((uint32_t)(kk >> 32) != 0u) ? 0x10000u : 0u;
        ordv[r] = idx | nz;
    }
    __syncthreads();
    {
        const int wid = t >> 6, lane = t & 63, e = lane & 31, h = lane >> 5;
        for (int blk = wid * 16; blk < wid * 16 + 16; ++blk) {
            uint32_t ue = ordv[blk * 32 + e];
            int widx = (int)((ue & 0xffffu) >> 5);
            int bpos = (int)(ue & 31u);
            uint32_t vM = 0;
#pragma unroll
            for (int half = 0; half < 2; ++half) {
                uint32_t wbuf[8];
#pragma unroll
                for (int k = 0; k < 8; ++k) {
                    int d = half * 16 + k * 2 + h;
                    uint32_t ud = ordv[blk * 32 + d] & 0xffffu;
                    wbuf[k] = abase[(size_t)ud * WORDS + widx];
                }
#pragma unroll
                for (int k = 0; k < 8; ++k) {
                    int d0 = half * 16 + k * 2;
                    unsigned long long bal = __ballot(((wbuf[k] >> bpos) & 1u) != 0u);
                    vM = (lane == d0    ) ? (uint32_t)bal         : vM;
                    vM = (lane == d0 + 1) ? (uint32_t)(bal >> 32) : vM;
                }
            }
            if (lane < 32) Mlds[blk * 32 + lane] = vM;
        }
    }
    __syncthreads();
    if (t < 64) {
        const int lane = t;
        const uint32_t* const rowp = abase + lane;
        uint32_t S = 0;
        uint32_t rbA[32], rbB[32];
        uint32_t u_c, m_c, u_n, m_n;
        u_c = ordv[lane & 31];
        m_c = Mlds[lane & 31];
#pragma unroll
        for (int d = 0; d < 32; ++d) {
            int ud = __builtin_amdgcn_readlane((int)u_c, d) & 0xffff;
            rbA[d] = rowp[(size_t)ud * WORDS];
        }
        auto do_block = [&](int blk, uint32_t (&rbC)[32], uint32_t (&rbN)[32]) {
            u_n = 0; m_n = 0;
            if (blk < 63) {
                u_n = ordv[(blk + 1) * 32 + (lane & 31)];
                m_n = Mlds[(blk + 1) * 32 + (lane & 31)];
#pragma unroll
                for (int d = 0; d < 32; ++d) {
                    int ud = __builtin_amdgcn_readlane((int)u_n, d) & 0xffff;
                    rbN[d] = rowp[(size_t)ud * WORDS];
                }
            }
            int wq  = (int)(((u_c & 0xffffu) >> 5) << 2);
            int bpv = (int)(u_c & 31u);
            int pm  = __builtin_amdgcn_ds_bpermute(wq, (int)S);
            bool a0 = (((u_c >> 16) & 1u) != 0u) && (((pm >> bpv) & 1) == 0);
            uint32_t alive = (uint32_t)__ballot((int)a0);
#pragma unroll
            for (int d = 0; d < 32; ++d) {
                uint32_t rowd = (uint32_t)__builtin_amdgcn_readlane((int)m_c, d);
                uint32_t mk = rowd & (0xFFFFFFFEu << d);
                alive = (alive & (1u << d)) ? (alive & ~mk) : alive;
            }
            uint32_t acc = 0;
#pragma unroll
            for (int d = 0; d < 32; ++d)
                acc |= (alive & (1u << d)) ? rbC[d] : 0u;
            S |= acc;
            u_c = u_n; m_c = m_n;
        };
        for (int blk = 0; blk < 64; blk += 2) {
            do_block(blk,     rbA, rbB);
            do_block(blk + 1, rbB, rbA);
        }
        Sarr[lane] = S;
    }
    __syncthreads();
    float* op = out + (size_t)bc * NN;
    for (int i = t; i < NN; i += 256) {
        float v = cf[i];
        bool sup = (Sarr[i >> 5] >> (i & 31)) & 1u;
        op[i] = (v > PRE_THR && !sup) ? v : 0.0f;
    }
}

extern "C" void kernel_launch(void* const* d_in, const int* in_sizes, int n_in,
                              void* d_out, int out_size, void* d_ws, size_t ws_size,
                              hipStream_t stream) {
    const float* bbs  = (const float*)d_in[0];   // [8,2048,4]
    const float* conf = (const float*)d_in[1];   // [8,32,2048]
    float* out = (float*)d_out;                  // [8,32,2048]

    const size_t adjB = (size_t)BB * NN * WORDS * sizeof(uint32_t);   // 4 MB
    const size_t ordB = (size_t)BB * CC * NN * sizeof(uint32_t);      // 2 MB
    const size_t mB   = ordB;                                          // 2 MB
    uint32_t* adj = (uint32_t*)d_ws;

    if (ws_size >= adjB + ordB + mB) {
        uint32_t* wsOrd = (uint32_t*)((char*)d_ws + adjB);
        uint32_t* wsM   = (uint32_t*)((char*)d_ws + adjB + ordB);
        adj_kernel    <<<dim3(NN / 16, BB), 256, 0, stream>>>(bbs, adj);
        sort_kernel   <<<BB * CC, 64, 0, stream>>>(conf, wsOrd);
        extract_kernel<<<BB * CC * 8, 256, 0, stream>>>(adj, wsOrd, wsM);
        scan_kernel   <<<BB * CC, 64, 0, stream>>>(conf, adj, wsOrd, wsM, out);
    } else if (ws_size >= adjB) {
        adj_kernel  <<<dim3(NN / 16, BB), 256, 0, stream>>>(bbs, adj);
        nms_fallback<<<BB * CC, 256, 0, stream>>>(conf, adj, out);
    }
}

// Round 5
// 200.653 us; speedup vs baseline: 1.3877x; 1.3877x over previous
//
#include <hip/hip_runtime.h>
#include <stdint.h>

// Keep IoU arithmetic bit-identical to an IEEE no-FMA reference:
#pragma clang fp contract(off)

#define BB   8
#define NN   2048
#define CC   32
#define WORDS 64           // uint32 words per 2048-bit row mask
#define NBLK 64            // rank blocks of 32
#define NMS_THR 0.45f
#define PRE_THR 0.005f
#define PADI(i) ((((i) >> 5) * 33) + ((i) & 31))   // padded SoA index
#define KPAD(i) ((i) + ((i) >> 4))                 // u64 key pad

typedef unsigned long long u64;

// ---------------- K1: per-image adjacency bitmask ----------------
// grid (128, 8): block (x,b) -> rows [x*16, x*16+16); wave -> 4 rows. 4 blocks/CU.
// Lane l owns output word l. Fast rcp path with exact-div fallback in a narrow
// guard band (rcp err ~1e-7 << 2e-5 band) -> decisions bit-identical to IEEE div.
__global__ __launch_bounds__(256) void adj_kernel(const float* __restrict__ bbs,
                                                  uint32_t* __restrict__ adj) {
    __shared__ float sx1[2112], sy1[2112], sx2[2112], sy2[2112];
    const int b = blockIdx.y;
    const int t = threadIdx.x;
    const float4* bp = (const float4*)bbs + (size_t)b * NN;
    for (int i = t; i < NN; i += 256) {
        float4 v = bp[i];
        int p = PADI(i);
        sx1[p] = v.x; sy1[p] = v.y; sx2[p] = v.z; sy2[p] = v.w;
    }
    __syncthreads();

    const int wave = t >> 6, lane = t & 63;
    const int row0 = blockIdx.x * 16 + wave * 4;
    const float THI = 0.45f * 1.00002f;
    const float TLO = 0.45f * 0.99998f;

    float ax1[4], ay1[4], ax2[4], ay2[4], areaA[4];
#pragma unroll
    for (int r = 0; r < 4; ++r) {
        int p = PADI(row0 + r);
        ax1[r] = sx1[p]; ay1[r] = sy1[p]; ax2[r] = sx2[p]; ay2[r] = sy2[p];
        areaA[r] = (ax2[r] - ax1[r]) * (ay2[r] - ay1[r]);
    }
    uint32_t w[4] = {0, 0, 0, 0};
#pragma unroll 4
    for (int j = 0; j < 32; ++j) {
        int p = lane * 33 + j;                 // bank (lane+j)%32: 2-way = free
        float bx1 = sx1[p], by1 = sy1[p], bx2 = sx2[p], by2 = sy2[p];
        float areaB = (bx2 - bx1) * (by2 - by1);
#pragma unroll
        for (int r = 0; r < 4; ++r) {
            float ltx = fmaxf(ax1[r], bx1), lty = fmaxf(ay1[r], by1);
            float rbx = fminf(ax2[r], bx2), rby = fminf(ay2[r], by2);
            float ww = fmaxf(rbx - ltx, 0.0f);
            float hh = fmaxf(rby - lty, 0.0f);
            float inter = ww * hh;
            float uni  = (areaA[r] + areaB) - inter;
            float unim = fmaxf(uni, 1e-12f);
            float q1 = inter * __builtin_amdgcn_rcpf(unim);
            bool hi = q1 > THI;
            bool lo = q1 < TLO;
            bool adjb;
            if (__builtin_expect(__any((int)!(hi || lo)), 0))
                adjb = (inter / unim) > NMS_THR;   // exact IEEE div, rare
            else
                adjb = hi;
            if (adjb) w[r] |= (1u << j);
        }
    }
#pragma unroll
    for (int r = 0; r < 4; ++r) {
        int row = row0 + r;
        uint32_t dmask = (lane == (row >> 5)) ? ~(1u << (row & 31)) : 0xFFFFFFFFu;
        adj[((size_t)b * NN + row) * WORDS + lane] = w[r] & dmask;
    }
}

// ---------------- K2: per-(b,c) bitonic sort, 1024 threads ----------------
// One CE per thread per stage; stage-pairs (j, j/2) fused in registers
// (4-element aligned groups) -> 35 LDS passes instead of 66.
__device__ __forceinline__ void ce_reg(u64& a, u64& b, bool up) {
    u64 mn = (a < b) ? a : b;
    u64 mx = (a < b) ? b : a;
    a = up ? mx : mn;
    b = up ? mn : mx;
}

__global__ __launch_bounds__(1024) void sort_kernel(const float* __restrict__ conf,
                                                    uint32_t* __restrict__ wsOrd) {
    __shared__ u64 keys[2176];   // KPAD(2047)=2174
    const int bc = blockIdx.x;
    const int t  = threadIdx.x;
    const float* cf = conf + (size_t)bc * NN;

    // ---- load + in-register k=2,k=4 (threads 0..511, float4 coalesced) ----
    if (t < 512) {
        const int g = 4 * t;
        float4 v = ((const float4*)cf)[t];
        float f0 = (v.x > PRE_THR) ? v.x : 0.0f;
        float f1 = (v.y > PRE_THR) ? v.y : 0.0f;
        float f2 = (v.z > PRE_THR) ? v.z : 0.0f;
        float f3 = (v.w > PRE_THR) ? v.w : 0.0f;
        u64 a0 = ((u64)__float_as_uint(f0) << 32) | (uint32_t)(NN - 1 - (g + 0));
        u64 a1 = ((u64)__float_as_uint(f1) << 32) | (uint32_t)(NN - 1 - (g + 1));
        u64 a2 = ((u64)__float_as_uint(f2) << 32) | (uint32_t)(NN - 1 - (g + 2));
        u64 a3 = ((u64)__float_as_uint(f3) << 32) | (uint32_t)(NN - 1 - (g + 3));
        // k=2: CE(g,g+1) up; CE(g+2,g+3) down
        ce_reg(a0, a1, true);
        ce_reg(a2, a3, false);
        // k=4: j=2 then j=1, dir from bit2 of g
        bool up4 = ((g & 4) == 0);
        ce_reg(a0, a2, up4); ce_reg(a1, a3, up4);
        ce_reg(a0, a1, up4); ce_reg(a2, a3, up4);
        keys[KPAD(g + 0)] = a0; keys[KPAD(g + 1)] = a1;
        keys[KPAD(g + 2)] = a2; keys[KPAD(g + 3)] = a3;
    }
    __syncthreads();

    // ---- main bitonic: k = 8 .. 2048, stage-pairs fused ----
    for (unsigned k = 8; k <= NN; k <<= 1) {
        unsigned j = k >> 1;
        while (j >= 2) {
            const unsigned h = j >> 1;
            if (t < 512) {
                unsigned g  = (((unsigned)t & ~(h - 1)) << 2) | ((unsigned)t & (h - 1));
                bool up = ((g & k) == 0);
                u64 e0 = keys[KPAD(g)];
                u64 e1 = keys[KPAD(g + h)];
                u64 e2 = keys[KPAD(g + j)];
                u64 e3 = keys[KPAD(g + j + h)];
                ce_reg(e0, e2, up); ce_reg(e1, e3, up);   // stage j
                ce_reg(e0, e1, up); ce_reg(e2, e3, up);   // stage h
                keys[KPAD(g)]         = e0;
                keys[KPAD(g + h)]     = e1;
                keys[KPAD(g + j)]     = e2;
                keys[KPAD(g + j + h)] = e3;
            }
            __syncthreads();
            j >>= 2;
        }
        if (j == 1) {   // lone final stage
            unsigned p  = (unsigned)t;
            unsigned i  = p << 1;
            bool up = ((i & k) == 0);
            u64 a = keys[KPAD(i)], d = keys[KPAD(i + 1)];
            ce_reg(a, d, up);
            keys[KPAD(i)] = a; keys[KPAD(i + 1)] = d;
            __syncthreads();
        }
    }

    uint32_t* ov = wsOrd + (size_t)bc * NN;
    for (int r = t; r < NN; r += 1024) {
        u64 kk = keys[KPAD(r)];
        uint32_t idx = (uint32_t)(NN - 1) - (uint32_t)(kk & 0xffffffffu);
        uint32_t nz  = ((uint32_t)(kk >> 32) != 0u) ? 0x10000u : 0u;
        ov[r] = idx | nz;
    }
}

// ---------------- K3: rank-space sub-adjacency extraction ----------------
// grid 2048 x 256: block (bc, chunk-of-8 rank-blocks); 8 blocks/CU -> latency hidden.
// Stores M'[d] = M[d] & (0xFFFFFFFE << d)  (later-rank mask pre-applied).
__global__ __launch_bounds__(256) void extract_kernel(const uint32_t* __restrict__ adj,
                                                      const uint32_t* __restrict__ wsOrd,
                                                      uint32_t* __restrict__ wsM) {
    const int blkid = blockIdx.x;
    const int bc = blkid >> 3, chunk = blkid & 7;
    const int b  = bc >> 5;
    const int t = threadIdx.x, wv = t >> 6, lane = t & 63, e = lane & 31, h = lane >> 5;
    const uint32_t* ov = wsOrd + (size_t)bc * NN;
    const uint32_t* ab = adj + (size_t)b * NN * WORDS;

    for (int blk = chunk * 8 + wv; blk < chunk * 8 + 8; blk += 4) {
        uint32_t ue = ov[blk * 32 + e];
        int widx = (int)((ue & 0xffffu) >> 5);
        int bpos = (int)(ue & 31u);
        uint32_t wb[16];
#pragma unroll
        for (int k = 0; k < 16; ++k) {
            uint32_t ud = ov[blk * 32 + k * 2 + h] & 0xffffu;
            wb[k] = ab[(size_t)ud * WORDS + widx];
        }
        uint32_t vM = 0;
#pragma unroll
        for (int k = 0; k < 16; ++k) {
            unsigned long long bal = __ballot(((wb[k] >> bpos) & 1u) != 0u);
            vM = (lane == 2 * k    ) ? (uint32_t)bal         : vM;
            vM = (lane == 2 * k + 1) ? (uint32_t)(bal >> 32) : vM;
        }
        if (lane < 32)
            wsM[(size_t)bc * NN + blk * 32 + lane] = vM & (0xFFFFFFFEu << lane);
    }
}

// ---------------- K4: serial blocked greedy scan + output ----------------
// grid 256 x 64 threads (one wave). S word l lives in lane l.
__global__ __launch_bounds__(64) void scan_kernel(const float* __restrict__ conf,
                                                  const uint32_t* __restrict__ adj,
                                                  const uint32_t* __restrict__ wsOrd,
                                                  const uint32_t* __restrict__ wsM,
                                                  float* __restrict__ out) {
    const int bc = blockIdx.x;
    const int b  = bc >> 5;
    const int lane = threadIdx.x;
    const uint32_t* ov = wsOrd + (size_t)bc * NN;
    const uint32_t* mv = wsM   + (size_t)bc * NN;
    const uint32_t* const rowp = adj + (size_t)b * NN * WORDS + lane;
    const float* cf = conf + (size_t)bc * NN;
    float* op = out + (size_t)bc * NN;

    uint32_t S = 0;
    uint32_t rbA[32], rbB[32];
    uint32_t u_c = ov[lane & 31];
    uint32_t m_c = mv[lane & 31];
    uint32_t u_n, m_n;
#pragma unroll
    for (int d = 0; d < 32; ++d) {
        int ud = __builtin_amdgcn_readlane((int)u_c, d) & 0xffff;
        rbA[d] = rowp[(size_t)ud * WORDS];
    }

    auto do_block = [&](int blk, uint32_t (&rbC)[32], uint32_t (&rbN)[32]) {
        u_n = 0; m_n = 0;
        if (blk < 63) {
            u_n = ov[(blk + 1) * 32 + (lane & 31)];
            m_n = mv[(blk + 1) * 32 + (lane & 31)];
#pragma unroll
            for (int d = 0; d < 32; ++d) {
                int ud = __builtin_amdgcn_readlane((int)u_n, d) & 0xffff;
                rbN[d] = rowp[(size_t)ud * WORDS];
            }
        }
        int wq  = (int)(((u_c & 0xffffu) >> 5) << 2);
        int bpv = (int)(u_c & 31u);
        int pm  = __builtin_amdgcn_ds_bpermute(wq, (int)S);
        bool a0 = (((u_c >> 16) & 1u) != 0u) && (((pm >> bpv) & 1) == 0);
        uint32_t alive = (uint32_t)__ballot((int)a0);
        if (alive) {
#pragma unroll
            for (int d = 0; d < 32; ++d) {
                uint32_t mk = (uint32_t)__builtin_amdgcn_readlane((int)m_c, d);  // pre-masked
                alive = (alive & (1u << d)) ? (alive & ~mk) : alive;
            }
            uint32_t acc = 0;
#pragma unroll
            for (int d = 0; d < 32; ++d)
                acc |= (alive & (1u << d)) ? rbC[d] : 0u;
            S |= acc;
        }
        u_c = u_n; m_c = m_n;
    };

    for (int blk = 0; blk < NBLK; blk += 2) {
        do_block(blk,     rbA, rbB);
        do_block(blk + 1, rbB, rbA);
    }

    // Output: suppressed-bit lookup via bpermute of register-resident S.
#pragma unroll 4
    for (int it = 0; it < 32; ++it) {
        int i = it * 64 + lane;
        int sw = __builtin_amdgcn_ds_bpermute(((i >> 5) & 63) << 2, (int)S);
        bool sup = (sw >> (i & 31)) & 1;
        float v = cf[i];
        op[i] = (v > PRE_THR && !sup) ? v : 0.0f;
    }
}

// ---------------- Fallback (ws too small): monolithic ----------------
__global__ __launch_bounds__(256) void nms_fallback(const float* __restrict__ conf,
                                                    const uint32_t* __restrict__ adj,
                                                    float* __restrict__ out) {
    __shared__ unsigned long long keys[NN];
    __shared__ uint32_t ordv[NN];
    __shared__ uint32_t Mlds[NBLK * 32];
    __shared__ uint32_t Sarr[WORDS];
    const int bc = blockIdx.x;
    const int b  = bc >> 5;
    const int t  = threadIdx.x;
    const float* cf = conf + (size_t)bc * NN;
    const uint32_t* const abase = adj + (size_t)b * NN * WORDS;

    for (int i = t; i < NN; i += 256) {
        float v  = cf[i];
        float vt = (v > PRE_THR) ? v : 0.0f;
        keys[i] = ((unsigned long long)__float_as_uint(vt) << 32) | (uint32_t)(NN - 1 - i);
    }
    __syncthreads();
    for (unsigned k = 2; k <= NN; k <<= 1)
        for (unsigned j = k >> 1; j > 0; j >>= 1) {
            for (unsigned p = t; p < NN / 2; p += 256) {
                unsigned i  = ((p & ~(j - 1)) << 1) | (p & (j - 1));
                unsigned ij = i | j;
                unsigned long long a = keys[i], d = keys[ij];
                bool up = ((i & k) == 0);
                if (up ? (a < d) : (a > d)) { keys[i] = d; keys[ij] = a; }
            }
            __syncthreads();
        }
    for (int r = t; r < NN; r += 256) {
        unsigned long long kk = keys[r];
        uint32_t idx = (uint32_t)(NN - 1) - (uint32_t)(kk & 0xffffffffu);
        uint32_t nz  = ((uint32_t)(kk >> 32) != 0u) ? 0x10000u : 0u;
        ordv[r] = idx | nz;
    }
    __syncthreads();
    {
        const int wid = t >> 6, lane = t & 63, e = lane & 31, h = lane >> 5;
        for (int blk = wid * 16; blk < wid * 16 + 16; ++blk) {
            uint32_t ue = ordv[blk * 32 + e];
            int widx = (int)((ue & 0xffffu) >> 5);
            int bpos = (int)(ue & 31u);
            uint32_t vM = 0;
#pragma unroll
            for (int half = 0; half < 2; ++half) {
                uint32_t wbuf[8];
#pragma unroll
                for (int k = 0; k < 8; ++k) {
                    int d = half * 16 + k * 2 + h;
                    uint32_t ud = ordv[blk * 32 + d] & 0xffffu;
                    wbuf[k] = abase[(size_t)ud * WORDS + widx];
                }
#pragma unroll
                for (int k = 0; k < 8; ++k) {
                    int d0 = half * 16 + k * 2;
                    unsigned long long bal = __ballot(((wbuf[k] >> bpos) & 1u) != 0u);
                    vM = (lane == d0    ) ? (uint32_t)bal         : vM;
                    vM = (lane == d0 + 1) ? (uint32_t)(bal >> 32) : vM;
                }
            }
            if (lane < 32) Mlds[blk * 32 + lane] = vM;
        }
    }
    __syncthreads();
    if (t < 64) {
        const int lane = t;
        const uint32_t* const rowp = abase + lane;
        uint32_t S = 0;
        uint32_t rbA[32], rbB[32];
        uint32_t u_c, m_c, u_n, m_n;
        u_c = ordv[lane & 31];
        m_c = Mlds[lane & 31];
#pragma unroll
        for (int d = 0; d < 32; ++d) {
            int ud = __builtin_amdgcn_readlane((int)u_c, d) & 0xffff;
            rbA[d] = rowp[(size_t)ud * WORDS];
        }
        auto do_block = [&](int blk, uint32_t (&rbC)[32], uint32_t (&rbN)[32]) {
            u_n = 0; m_n = 0;
            if (blk < 63) {
                u_n = ordv[(blk + 1) * 32 + (lane & 31)];
                m_n = Mlds[(blk + 1) * 32 + (lane & 31)];
#pragma unroll
                for (int d = 0; d < 32; ++d) {
                    int ud = __builtin_amdgcn_readlane((int)u_n, d) & 0xffff;
                    rbN[d] = rowp[(size_t)ud * WORDS];
                }
            }
            int wq  = (int)(((u_c & 0xffffu) >> 5) << 2);
            int bpv = (int)(u_c & 31u);
            int pm  = __builtin_amdgcn_ds_bpermute(wq, (int)S);
            bool a0 = (((u_c >> 16) & 1u) != 0u) && (((pm >> bpv) & 1) == 0);
            uint32_t alive = (uint32_t)__ballot((int)a0);
#pragma unroll
            for (int d = 0; d < 32; ++d) {
                uint32_t rowd = (uint32_t)__builtin_amdgcn_readlane((int)m_c, d);
                uint32_t mk = rowd & (0xFFFFFFFEu << d);
                alive = (alive & (1u << d)) ? (alive & ~mk) : alive;
            }
            uint32_t acc = 0;
#pragma unroll
            for (int d = 0; d < 32; ++d)
                acc |= (alive & (1u << d)) ? rbC[d] : 0u;
            S |= acc;
            u_c = u_n; m_c = m_n;
        };
        for (int blk = 0; blk < 64; blk += 2) {
            do_block(blk,     rbA, rbB);
            do_block(blk + 1, rbB, rbA);
        }
        Sarr[lane] = S;
    }
    __syncthreads();
    float* op = out + (size_t)bc * NN;
    for (int i = t; i < NN; i += 256) {
        float v = cf[i];
        bool sup = (Sarr[i >> 5] >> (i & 31)) & 1u;
        op[i] = (v > PRE_THR && !sup) ? v : 0.0f;
    }
}

extern "C" void kernel_launch(void* const* d_in, const int* in_sizes, int n_in,
                              void* d_out, int out_size, void* d_ws, size_t ws_size,
                              hipStream_t stream) {
    const float* bbs  = (const float*)d_in[0];   // [8,2048,4]
    const float* conf = (const float*)d_in[1];   // [8,32,2048]
    float* out = (float*)d_out;                  // [8,32,2048]

    const size_t adjB = (size_t)BB * NN * WORDS * sizeof(uint32_t);   // 4 MB
    const size_t ordB = (size_t)BB * CC * NN * sizeof(uint32_t);      // 2 MB
    const size_t mB   = ordB;                                          // 2 MB
    uint32_t* adj = (uint32_t*)d_ws;

    if (ws_size >= adjB + ordB + mB) {
        uint32_t* wsOrd = (uint32_t*)((char*)d_ws + adjB);
        uint32_t* wsM   = (uint32_t*)((char*)d_ws + adjB + ordB);
        adj_kernel    <<<dim3(NN / 16, BB), 256, 0, stream>>>(bbs, adj);
        sort_kernel   <<<BB * CC, 1024, 0, stream>>>(conf, wsOrd);
        extract_kernel<<<BB * CC * 8, 256, 0, stream>>>(adj, wsOrd, wsM);
        scan_kernel   <<<BB * CC, 64, 0, stream>>>(conf, adj, wsOrd, wsM, out);
    } else if (ws_size >= adjB) {
        adj_kernel  <<<dim3(NN / 16, BB), 256, 0, stream>>>(bbs, adj);
        nms_fallback<<<BB * CC, 256, 0, stream>>>(conf, adj, out);
    }
}

// Round 6
// 166.763 us; speedup vs baseline: 1.6697x; 1.2032x over previous
//
#include <hip/hip_runtime.h>
#include <stdint.h>

// Keep IoU arithmetic bit-identical to an IEEE no-FMA reference:
#pragma clang fp contract(off)

#define BB   8
#define NN   2048
#define CC   32
#define WORDS 64           // uint32 words per 2048-bit row mask
#define NBLK 64            // rank blocks of 32
#define NMS_THR 0.45f
#define PRE_THR 0.005f
#define PADI(i) ((((i) >> 5) * 33) + ((i) & 31))   // padded SoA index
#define KPAD(i) ((i) + ((i) >> 4))                 // u64 key pad

typedef unsigned long long u64;

// ---------------- K1: per-image adjacency bitmask ----------------
__global__ __launch_bounds__(256) void adj_kernel(const float* __restrict__ bbs,
                                                  uint32_t* __restrict__ adj) {
    __shared__ float sx1[2112], sy1[2112], sx2[2112], sy2[2112];
    const int b = blockIdx.y;
    const int t = threadIdx.x;
    const float4* bp = (const float4*)bbs + (size_t)b * NN;
    for (int i = t; i < NN; i += 256) {
        float4 v = bp[i];
        int p = PADI(i);
        sx1[p] = v.x; sy1[p] = v.y; sx2[p] = v.z; sy2[p] = v.w;
    }
    __syncthreads();

    const int wave = t >> 6, lane = t & 63;
    const int row0 = blockIdx.x * 16 + wave * 4;
    const float THI = 0.45f * 1.00002f;
    const float TLO = 0.45f * 0.99998f;

    float ax1[4], ay1[4], ax2[4], ay2[4], areaA[4];
#pragma unroll
    for (int r = 0; r < 4; ++r) {
        int p = PADI(row0 + r);
        ax1[r] = sx1[p]; ay1[r] = sy1[p]; ax2[r] = sx2[p]; ay2[r] = sy2[p];
        areaA[r] = (ax2[r] - ax1[r]) * (ay2[r] - ay1[r]);
    }
    uint32_t w[4] = {0, 0, 0, 0};
#pragma unroll 4
    for (int j = 0; j < 32; ++j) {
        int p = lane * 33 + j;                 // bank (lane+j)%32: 2-way = free
        float bx1 = sx1[p], by1 = sy1[p], bx2 = sx2[p], by2 = sy2[p];
        float areaB = (bx2 - bx1) * (by2 - by1);
#pragma unroll
        for (int r = 0; r < 4; ++r) {
            float ltx = fmaxf(ax1[r], bx1), lty = fmaxf(ay1[r], by1);
            float rbx = fminf(ax2[r], bx2), rby = fminf(ay2[r], by2);
            float ww = fmaxf(rbx - ltx, 0.0f);
            float hh = fmaxf(rby - lty, 0.0f);
            float inter = ww * hh;
            float uni  = (areaA[r] + areaB) - inter;
            float unim = fmaxf(uni, 1e-12f);
            float q1 = inter * __builtin_amdgcn_rcpf(unim);
            bool hi = q1 > THI;
            bool lo = q1 < TLO;
            bool adjb;
            if (__builtin_expect(__any((int)!(hi || lo)), 0))
                adjb = (inter / unim) > NMS_THR;   // exact IEEE div, rare
            else
                adjb = hi;
            if (adjb) w[r] |= (1u << j);
        }
    }
#pragma unroll
    for (int r = 0; r < 4; ++r) {
        int row = row0 + r;
        uint32_t dmask = (lane == (row >> 5)) ? ~(1u << (row & 31)) : 0xFFFFFFFFu;
        adj[((size_t)b * NN + row) * WORDS + lane] = w[r] & dmask;
    }
}

// ---------------- K2: per-(b,c) bitonic sort, 1024 threads ----------------
__device__ __forceinline__ void ce_reg(u64& a, u64& b, bool up) {
    u64 mn = (a < b) ? a : b;
    u64 mx = (a < b) ? b : a;
    a = up ? mx : mn;
    b = up ? mn : mx;
}

__global__ __launch_bounds__(1024) void sort_kernel(const float* __restrict__ conf,
                                                    uint32_t* __restrict__ wsOrd) {
    __shared__ u64 keys[2176];   // KPAD(2047)=2174
    const int bc = blockIdx.x;
    const int t  = threadIdx.x;
    const float* cf = conf + (size_t)bc * NN;

    if (t < 512) {
        const int g = 4 * t;
        float4 v = ((const float4*)cf)[t];
        float f0 = (v.x > PRE_THR) ? v.x : 0.0f;
        float f1 = (v.y > PRE_THR) ? v.y : 0.0f;
        float f2 = (v.z > PRE_THR) ? v.z : 0.0f;
        float f3 = (v.w > PRE_THR) ? v.w : 0.0f;
        u64 a0 = ((u64)__float_as_uint(f0) << 32) | (uint32_t)(NN - 1 - (g + 0));
        u64 a1 = ((u64)__float_as_uint(f1) << 32) | (uint32_t)(NN - 1 - (g + 1));
        u64 a2 = ((u64)__float_as_uint(f2) << 32) | (uint32_t)(NN - 1 - (g + 2));
        u64 a3 = ((u64)__float_as_uint(f3) << 32) | (uint32_t)(NN - 1 - (g + 3));
        ce_reg(a0, a1, true);
        ce_reg(a2, a3, false);
        bool up4 = ((g & 4) == 0);
        ce_reg(a0, a2, up4); ce_reg(a1, a3, up4);
        ce_reg(a0, a1, up4); ce_reg(a2, a3, up4);
        keys[KPAD(g + 0)] = a0; keys[KPAD(g + 1)] = a1;
        keys[KPAD(g + 2)] = a2; keys[KPAD(g + 3)] = a3;
    }
    __syncthreads();

    for (unsigned k = 8; k <= NN; k <<= 1) {
        unsigned j = k >> 1;
        while (j >= 2) {
            const unsigned h = j >> 1;
            if (t < 512) {
                unsigned g  = (((unsigned)t & ~(h - 1)) << 2) | ((unsigned)t & (h - 1));
                bool up = ((g & k) == 0);
                u64 e0 = keys[KPAD(g)];
                u64 e1 = keys[KPAD(g + h)];
                u64 e2 = keys[KPAD(g + j)];
                u64 e3 = keys[KPAD(g + j + h)];
                ce_reg(e0, e2, up); ce_reg(e1, e3, up);
                ce_reg(e0, e1, up); ce_reg(e2, e3, up);
                keys[KPAD(g)]         = e0;
                keys[KPAD(g + h)]     = e1;
                keys[KPAD(g + j)]     = e2;
                keys[KPAD(g + j + h)] = e3;
            }
            __syncthreads();
            j >>= 2;
        }
        if (j == 1) {
            unsigned i  = (unsigned)t << 1;
            bool up = ((i & k) == 0);
            u64 a = keys[KPAD(i)], d = keys[KPAD(i + 1)];
            ce_reg(a, d, up);
            keys[KPAD(i)] = a; keys[KPAD(i + 1)] = d;
            __syncthreads();
        }
    }

    uint32_t* ov = wsOrd + (size_t)bc * NN;
    for (int r = t; r < NN; r += 1024) {
        u64 kk = keys[KPAD(r)];
        uint32_t idx = (uint32_t)(NN - 1) - (uint32_t)(kk & 0xffffffffu);
        uint32_t nz  = ((uint32_t)(kk >> 32) != 0u) ? 0x10000u : 0u;
        ov[r] = idx | nz;
    }
}

// ---------------- K3: rank-space sub-adjacency extraction ----------------
__global__ __launch_bounds__(256) void extract_kernel(const uint32_t* __restrict__ adj,
                                                      const uint32_t* __restrict__ wsOrd,
                                                      uint32_t* __restrict__ wsM) {
    const int blkid = blockIdx.x;
    const int bc = blkid >> 3, chunk = blkid & 7;
    const int b  = bc >> 5;
    const int t = threadIdx.x, wv = t >> 6, lane = t & 63, e = lane & 31, h = lane >> 5;
    const uint32_t* ov = wsOrd + (size_t)bc * NN;
    const uint32_t* ab = adj + (size_t)b * NN * WORDS;

    for (int blk = chunk * 8 + wv; blk < chunk * 8 + 8; blk += 4) {
        uint32_t ue = ov[blk * 32 + e];
        int widx = (int)((ue & 0xffffu) >> 5);
        int bpos = (int)(ue & 31u);
        uint32_t wb[16];
#pragma unroll
        for (int k = 0; k < 16; ++k) {
            uint32_t ud = ov[blk * 32 + k * 2 + h] & 0xffffu;
            wb[k] = ab[(size_t)ud * WORDS + widx];
        }
        uint32_t vM = 0;
#pragma unroll
        for (int k = 0; k < 16; ++k) {
            unsigned long long bal = __ballot(((wb[k] >> bpos) & 1u) != 0u);
            vM = (lane == 2 * k    ) ? (uint32_t)bal         : vM;
            vM = (lane == 2 * k + 1) ? (uint32_t)(bal >> 32) : vM;
        }
        if (lane < 32)
            wsM[(size_t)bc * NN + blk * 32 + lane] = vM & (0xFFFFFFFEu << lane);
    }
}

// ---------------- K4: producer/consumer serial scan + output ----------------
// 256 threads: waves 1-3 stream adjacency rows (next 8-block chunk) into a
// 64KB LDS double buffer; wave 0 runs the serial greedy resolve from LDS.
// No persistent per-thread row arrays -> no scratch spill.
__global__ __launch_bounds__(256) void scan_kernel(const float* __restrict__ conf,
                                                   const uint32_t* __restrict__ adj,
                                                   const uint32_t* __restrict__ wsOrd,
                                                   const uint32_t* __restrict__ wsM,
                                                   float* __restrict__ out) {
    __shared__ uint32_t buf[2][256][64];   // 128 KB: 2 x (8 blocks x 32 rows x 64 words)
    __shared__ uint32_t ordL[NN];          // 8 KB
    __shared__ uint32_t Ml[NN];            // 8 KB (pre-masked M')
    __shared__ uint32_t Sarr[WORDS];
    const int bc = blockIdx.x;
    const int b  = bc >> 5;
    const int t  = threadIdx.x, wid = t >> 6, lane = t & 63;
    const uint32_t* ov = wsOrd + (size_t)bc * NN;
    const uint32_t* mv = wsM   + (size_t)bc * NN;
    const uint32_t* ab = adj + (size_t)b * NN * WORDS;
    const float* cf = conf + (size_t)bc * NN;
    float* op = out + (size_t)bc * NN;

    for (int i = t; i < NN; i += 256) { ordL[i] = ov[i]; Ml[i] = mv[i]; }
    __syncthreads();

    // Fill chunk 0 (all 4 waves; row r covered by wave r%4).
    for (int r = wid; r < 256; r += 4) {
        uint32_t ud = ordL[r] & 0xffffu;               // wave-uniform broadcast read
        buf[0][r][lane] = ab[(size_t)ud * WORDS + lane];   // 256B coalesced
    }
    __syncthreads();

    uint32_t S = 0;
    for (int c = 0; c < 8; ++c) {
        const int cb = c & 1, nb = cb ^ 1;
        if (wid != 0) {
            // ---- producers: stream chunk c+1 ----
            if (c < 7) {
                const int base = (c + 1) * 256;
                for (int r = wid - 1; r < 256; r += 3) {
                    uint32_t ud = ordL[base + r] & 0xffffu;
                    buf[nb][r][lane] = ab[(size_t)ud * WORDS + lane];
                }
            }
        } else {
            // ---- consumer: serial resolve of chunk c's 8 blocks ----
            for (int k = 0; k < 8; ++k) {
                const int blk = c * 8 + k;
                uint32_t u = ordL[blk * 32 + (lane & 31)];
                uint32_t m = Ml[blk * 32 + (lane & 31)];
                int wq = (int)(((u & 0xffffu) >> 5) << 2);
                int pm = __builtin_amdgcn_ds_bpermute(wq, (int)S);
                uint32_t rw[32];
#pragma unroll
                for (int d = 0; d < 32; ++d)
                    rw[d] = buf[cb][k * 32 + d][lane];  // bank=lane%32, 2-way free
                bool a0 = (((u >> 16) & 1u) != 0u) && (((pm >> (u & 31u)) & 1) == 0);
                uint32_t alive = (uint32_t)__ballot((int)a0);
                if (alive) {
#pragma unroll
                    for (int d = 0; d < 32; ++d) {
                        uint32_t mk = (uint32_t)__builtin_amdgcn_readlane((int)m, d);
                        alive = (alive & (1u << d)) ? (alive & ~mk) : alive;
                    }
                    uint32_t acc = 0;
#pragma unroll
                    for (int d = 0; d < 32; ++d)
                        acc |= (alive & (1u << d)) ? rw[d] : 0u;
                    S |= acc;
                }
            }
        }
        __syncthreads();
    }
    if (wid == 0) Sarr[lane] = S;
    __syncthreads();

#pragma unroll 2
    for (int i = t; i < NN; i += 256) {
        float v = cf[i];
        bool sup = (Sarr[i >> 5] >> (i & 31)) & 1u;
        op[i] = (v > PRE_THR && !sup) ? v : 0.0f;
    }
}

// ---------------- Fallback (ws too small): monolithic ----------------
__global__ __launch_bounds__(256) void nms_fallback(const float* __restrict__ conf,
                                                    const uint32_t* __restrict__ adj,
                                                    float* __restrict__ out) {
    __shared__ unsigned long long keys[NN];
    __shared__ uint32_t ordv[NN];
    __shared__ uint32_t Mlds[NBLK * 32];
    __shared__ uint32_t Sarr[WORDS];
    const int bc = blockIdx.x;
    const int b  = bc >> 5;
    const int t  = threadIdx.x;
    const float* cf = conf + (size_t)bc * NN;
    const uint32_t* const abase = adj + (size_t)b * NN * WORDS;

    for (int i = t; i < NN; i += 256) {
        float v  = cf[i];
        float vt = (v > PRE_THR) ? v : 0.0f;
        keys[i] = ((unsigned long long)__float_as_uint(vt) << 32) | (uint32_t)(NN - 1 - i);
    }
    __syncthreads();
    for (unsigned k = 2; k <= NN; k <<= 1)
        for (unsigned j = k >> 1; j > 0; j >>= 1) {
            for (unsigned p = t; p < NN / 2; p += 256) {
                unsigned i  = ((p & ~(j - 1)) << 1) | (p & (j - 1));
                unsigned ij = i | j;
                unsigned long long a = keys[i], d = keys[ij];
                bool up = ((i & k) == 0);
                if (up ? (a < d) : (a > d)) { keys[i] = d; keys[ij] = a; }
            }
            __syncthreads();
        }
    for (int r = t; r < NN; r += 256) {
        unsigned long long kk = keys[r];
        uint32_t idx = (uint32_t)(NN - 1) - (uint32_t)(kk & 0xffffffffu);
        uint32_t nz  = ((uint32_t)(kk >> 32) != 0u) ? 0x10000u : 0u;
        ordv[r] = idx | nz;
    }
    __syncthreads();
    {
        const int wid = t >> 6, lane = t & 63, e = lane & 31, h = lane >> 5;
        for (int blk = wid * 16; blk < wid * 16 + 16; ++blk) {
            uint32_t ue = ordv[blk * 32 + e];
            int widx = (int)((ue & 0xffffu) >> 5);
            int bpos = (int)(ue & 31u);
            uint32_t vM = 0;
#pragma unroll
            for (int half = 0; half < 2; ++half) {
                uint32_t wbuf[8];
#pragma unroll
                for (int k = 0; k < 8; ++k) {
                    int d = half * 16 + k * 2 + h;
                    uint32_t ud = ordv[blk * 32 + d] & 0xffffu;
                    wbuf[k] = abase[(size_t)ud * WORDS + widx];
                }
#pragma unroll
                for (int k = 0; k < 8; ++k) {
                    int d0 = half * 16 + k * 2;
                    unsigned long long bal = __ballot(((wbuf[k] >> bpos) & 1u) != 0u);
                    vM = (lane == d0    ) ? (uint32_t)bal         : vM;
                    vM = (lane == d0 + 1) ? (uint32_t)(bal >> 32) : vM;
                }
            }
            if (lane < 32) Mlds[blk * 32 + lane] = vM;
        }
    }
    __syncthreads();
    if (t < 64) {
        const int lane = t;
        const uint32_t* const rowp = abase + lane;
        uint32_t S = 0;
        uint32_t rbA[32], rbB[32];
        uint32_t u_c, m_c, u_n, m_n;
        u_c = ordv[lane & 31];
        m_c = Mlds[lane & 31];
#pragma unroll
        for (int d = 0; d < 32; ++d) {
            int ud = __builtin_amdgcn_readlane((int)u_c, d) & 0xffff;
            rbA[d] = rowp[(size_t)ud * WORDS];
        }
        auto do_block = [&](int blk, uint32_t (&rbC)[32], uint32_t (&rbN)[32]) {
            u_n = 0; m_n = 0;
            if (blk < 63) {
                u_n = ordv[(blk + 1) * 32 + (lane & 31)];
                m_n = Mlds[(blk + 1) * 32 + (lane & 31)];
#pragma unroll
                for (int d = 0; d < 32; ++d) {
                    int ud = __builtin_amdgcn_readlane((int)u_n, d) & 0xffff;
                    rbN[d] = rowp[(size_t)ud * WORDS];
                }
            }
            int wq  = (int)(((u_c & 0xffffu) >> 5) << 2);
            int bpv = (int)(u_c & 31u);
            int pm  = __builtin_amdgcn_ds_bpermute(wq, (int)S);
            bool a0 = (((u_c >> 16) & 1u) != 0u) && (((pm >> bpv) & 1) == 0);
            uint32_t alive = (uint32_t)__ballot((int)a0);
#pragma unroll
            for (int d = 0; d < 32; ++d) {
                uint32_t rowd = (uint32_t)__builtin_amdgcn_readlane((int)m_c, d);
                uint32_t mk = rowd & (0xFFFFFFFEu << d);
                alive = (alive & (1u << d)) ? (alive & ~mk) : alive;
            }
            uint32_t acc = 0;
#pragma unroll
            for (int d = 0; d < 32; ++d)
                acc |= (alive & (1u << d)) ? rbC[d] : 0u;
            S |= acc;
            u_c = u_n; m_c = m_n;
        };
        for (int blk = 0; blk < 64; blk += 2) {
            do_block(blk,     rbA, rbB);
            do_block(blk + 1, rbB, rbA);
        }
        Sarr[lane] = S;
    }
    __syncthreads();
    float* op = out + (size_t)bc * NN;
    for (int i = t; i < NN; i += 256) {
        float v = cf[i];
        bool sup = (Sarr[i >> 5] >> (i & 31)) & 1u;
        op[i] = (v > PRE_THR && !sup) ? v : 0.0f;
    }
}

extern "C" void kernel_launch(void* const* d_in, const int* in_sizes, int n_in,
                              void* d_out, int out_size, void* d_ws, size_t ws_size,
                              hipStream_t stream) {
    const float* bbs  = (const float*)d_in[0];   // [8,2048,4]
    const float* conf = (const float*)d_in[1];   // [8,32,2048]
    float* out = (float*)d_out;                  // [8,32,2048]

    const size_t adjB = (size_t)BB * NN * WORDS * sizeof(uint32_t);   // 4 MB
    const size_t ordB = (size_t)BB * CC * NN * sizeof(uint32_t);      // 2 MB
    const size_t mB   = ordB;                                          // 2 MB
    uint32_t* adj = (uint32_t*)d_ws;

    if (ws_size >= adjB + ordB + mB) {
        uint32_t* wsOrd = (uint32_t*)((char*)d_ws + adjB);
        uint32_t* wsM   = (uint32_t*)((char*)d_ws + adjB + ordB);
        adj_kernel    <<<dim3(NN / 16, BB), 256, 0, stream>>>(bbs, adj);
        sort_kernel   <<<BB * CC, 1024, 0, stream>>>(conf, wsOrd);
        extract_kernel<<<BB * CC * 8, 256, 0, stream>>>(adj, wsOrd, wsM);
        scan_kernel   <<<BB * CC, 256, 0, stream>>>(conf, adj, wsOrd, wsM, out);
    } else if (ws_size >= adjB) {
        adj_kernel  <<<dim3(NN / 16, BB), 256, 0, stream>>>(bbs, adj);
        nms_fallback<<<BB * CC, 256, 0, stream>>>(conf, adj, out);
    }
}